// Round 9
// baseline (438.334 us; speedup 1.0000x reference)
//
#include <hip/hip_runtime.h>

#define NN 100000
#define NE 1600000
#define D 64
#define NB ((NN + 255) / 256)   // 391 scan blocks
#define SCAN2_T 512             // single-block scan width, >= NB

// ---------------------------------------------------------------------------
// K1: degree histogram. int4-vectorized edge read; 1.6M int atomics on a
// 400KB L2-resident array. (Privatization tested r8: no effect — reverted.)
// ---------------------------------------------------------------------------
__global__ __launch_bounds__(256) void degree_hist(const int* __restrict__ dst,
                                                   int* __restrict__ deg) {
    const int n4 = NE / 4;
    for (int i = blockIdx.x * blockDim.x + threadIdx.x; i < n4;
         i += gridDim.x * blockDim.x) {
        const int4 d = reinterpret_cast<const int4*>(dst)[i];
        atomicAdd(&deg[d.x], 1);
        atomicAdd(&deg[d.y], 1);
        atomicAdd(&deg[d.z], 1);
        atomicAdd(&deg[d.w], 1);
    }
}

// ---------------------------------------------------------------------------
// K2a: per-block exclusive scan of deg (256/block).
// ---------------------------------------------------------------------------
__global__ __launch_bounds__(256) void scan1(const int* __restrict__ deg,
                                             int* __restrict__ partial,
                                             int* __restrict__ blockSums) {
    const int t = threadIdx.x;
    const int i = blockIdx.x * 256 + t;
    const int lane = t & 63, wid = t >> 6;
    const int orig = (i < NN) ? deg[i] : 0;
    int v = orig;
#pragma unroll
    for (int off = 1; off < 64; off <<= 1) {
        int n = __shfl_up(v, off, 64);
        if (lane >= off) v += n;
    }
    __shared__ int wsum[4];
    if (lane == 63) wsum[wid] = v;
    __syncthreads();
    if (t == 0) {
        int s = 0;
#pragma unroll
        for (int w = 0; w < 4; ++w) { int tmp = wsum[w]; wsum[w] = s; s += tmp; }
    }
    __syncthreads();
    const int incl = v + wsum[wid];
    if (i < NN) partial[i] = incl - orig;
    if (t == 255) blockSums[blockIdx.x] = incl;
}

// ---------------------------------------------------------------------------
// K2b: single-block exclusive scan of the NB block sums (391 <= 512).
// ---------------------------------------------------------------------------
__global__ __launch_bounds__(SCAN2_T) void scan2(int* __restrict__ blockSums) {
    __shared__ int sm[SCAN2_T];
    const int t = threadIdx.x;
    const int orig = (t < NB) ? blockSums[t] : 0;
    sm[t] = orig;
    __syncthreads();
    for (int off = 1; off < SCAN2_T; off <<= 1) {
        int v = (t >= off) ? sm[t - off] : 0;
        __syncthreads();
        sm[t] += v;
        __syncthreads();
    }
    if (t < NB) blockSums[t] = sm[t] - orig;   // exclusive
}

// ---------------------------------------------------------------------------
// K2c: offs[i] = partial[i] + blockOffset; cursor copy for bucket fill.
// ---------------------------------------------------------------------------
__global__ __launch_bounds__(256) void scan3(const int* __restrict__ partial,
                                             const int* __restrict__ blockSums,
                                             int* __restrict__ offs,
                                             int* __restrict__ cursor) {
    const int i = blockIdx.x * 256 + threadIdx.x;
    if (i < NN) {
        const int o = partial[i] + blockSums[blockIdx.x];
        offs[i] = o;
        cursor[i] = o;
    }
}

// ---------------------------------------------------------------------------
// K3: bucket fill. csr[offs[dst]..] = src per edge. NEW: csr stores are
// NON-TEMPORAL — the scattered 4B stores otherwise write-allocate 128B L2
// lines that thrash (csr 6.4MB > 4MB per-XCD L2, ~32 temporally-spread
// writes/line). Streaming them to HBM as masked sector writes removes the
// fill/evict/refetch loop. K4 re-reads csr once, sequentially (cheap).
// ---------------------------------------------------------------------------
__global__ __launch_bounds__(256) void bucket_fill(const int* __restrict__ src,
                                                   const int* __restrict__ dst,
                                                   int* __restrict__ cursor,
                                                   int* __restrict__ csr) {
    const int n4 = NE / 4;
    for (int i = blockIdx.x * blockDim.x + threadIdx.x; i < n4;
         i += gridDim.x * blockDim.x) {
        const int4 d = reinterpret_cast<const int4*>(dst)[i];
        const int4 s = reinterpret_cast<const int4*>(src)[i];
        __builtin_nontemporal_store(s.x, &csr[atomicAdd(&cursor[d.x], 1)]);
        __builtin_nontemporal_store(s.y, &csr[atomicAdd(&cursor[d.y], 1)]);
        __builtin_nontemporal_store(s.z, &csr[atomicAdd(&cursor[d.z], 1)]);
        __builtin_nontemporal_store(s.w, &csr[atomicAdd(&cursor[d.w], 1)]);
    }
}

// ---------------------------------------------------------------------------
// K4: fused per-node gather-sum + transform + bias + L2-normalize + colsum.
// 64 lanes = 4 edge-slots x 16 lanes x float4; W in LDS. NEW: h stores are
// non-temporal (h never re-read on device) so the 25.6MB output stream stops
// evicting x from L2 -> higher gather hit rate.
// ---------------------------------------------------------------------------
__global__ __launch_bounds__(256) void gather_transform_norm(
        const float* __restrict__ x, const int* __restrict__ csr,
        const int* __restrict__ offs, const int* __restrict__ deg,
        const float* __restrict__ W, const float* __restrict__ b,
        float* __restrict__ h, float* __restrict__ colsum) {
    const int lane = threadIdx.x & 63;
    const int wid  = threadIdx.x >> 6;
    const int grp  = lane >> 4;   // edge slot 0..3
    const int sub  = lane & 15;   // feature slice (features 4*sub..4*sub+3)

    __shared__ float Wt[64 * 65];     // Wt[l*65+k] = W[k][l]
    __shared__ float smem[4][64];
    for (int idx = threadIdx.x; idx < 64 * 64; idx += 256) {
        const int k = idx >> 6, l = idx & 63;
        Wt[l * 65 + k] = W[idx];
    }
    __syncthreads();
    const float bj = b[lane];
    const float* wrow = &Wt[lane * 65];

    const int waveId = (blockIdx.x * blockDim.x + threadIdx.x) >> 6;
    const int nWaves = (gridDim.x * blockDim.x) >> 6;
    float csum = 0.f;
    for (int node = waveId; node < NN; node += nWaves) {
        const int start = offs[node];
        const int cnt   = deg[node];
        float ax = 0.f, ay = 0.f, az = 0.f, aw = 0.f;
        for (int c0 = 0; c0 < cnt; c0 += 64) {
            const int pos  = start + c0 + lane;
            const int idxv = (pos < NE) ? csr[pos] : 0;   // coalesced, guarded
            const int m = (cnt - c0 < 64) ? (cnt - c0) : 64;
#pragma unroll 4
            for (int j = 0; j < m; j += 4) {
                const int e = j + grp;
                const int s = __shfl(idxv, e, 64);        // ds_bpermute
                if (e < m) {
                    const float4 v = *reinterpret_cast<const float4*>(
                        x + (size_t)s * D + 4 * sub);     // 1KB/wave, 4 rows
                    ax += v.x; ay += v.y; az += v.z; aw += v.w;
                }
            }
        }
        // reduce the 4 edge-slots: lanes {l, l+16, l+32, l+48} share a slice
#pragma unroll
        for (int off = 16; off <= 32; off <<= 1) {
            ax += __shfl_xor(ax, off, 64);
            ay += __shfl_xor(ay, off, 64);
            az += __shfl_xor(az, off, 64);
            aw += __shfl_xor(aw, off, 64);
        }
        // transform: v[lane] = b[lane] + sum_k acc[k] * W[k][lane];
        // acc[4*k0+c] lives in lane k0, float4 component c.
        float v = bj;
#pragma unroll
        for (int k0 = 0; k0 < 16; ++k0) {
            const float a0 = __shfl(ax, k0, 64);
            const float a1 = __shfl(ay, k0, 64);
            const float a2 = __shfl(az, k0, 64);
            const float a3 = __shfl(aw, k0, 64);
            v = fmaf(a0, wrow[4 * k0 + 0], v);
            v = fmaf(a1, wrow[4 * k0 + 1], v);
            v = fmaf(a2, wrow[4 * k0 + 2], v);
            v = fmaf(a3, wrow[4 * k0 + 3], v);
        }
        float ss = v * v;
#pragma unroll
        for (int off = 32; off > 0; off >>= 1) ss += __shfl_xor(ss, off, 64);
        v = v / fmaxf(sqrtf(ss), 1e-12f);
        __builtin_nontemporal_store(v, &h[(size_t)node * D + lane]);
        csum += v;
    }
    smem[wid][lane] = csum;
    __syncthreads();
    if (wid == 0) {
        const float t = smem[0][lane] + smem[1][lane] + smem[2][lane] + smem[3][lane];
        atomicAdd(&colsum[lane], t);
    }
}

// ---------------------------------------------------------------------------
// K5: logits = dot(colsum/NN, wc) + bc.  One wave.
// ---------------------------------------------------------------------------
__global__ void finalize(const float* __restrict__ colsum,
                         const float* __restrict__ wc,
                         const float* __restrict__ bc,
                         float* __restrict__ out0) {
    const int lane = threadIdx.x;
    float v = colsum[lane] * (1.0f / (float)NN) * wc[lane];
#pragma unroll
    for (int off = 32; off > 0; off >>= 1) v += __shfl_xor(v, off, 64);
    if (lane == 0) out0[0] = v + bc[0];
}

extern "C" void kernel_launch(void* const* d_in, const int* in_sizes, int n_in,
                              void* d_out, int out_size, void* d_ws, size_t ws_size,
                              hipStream_t stream) {
    const float* x   = (const float*)d_in[0];
    const float* W   = (const float*)d_in[1];
    const float* b   = (const float*)d_in[2];
    const float* wc  = (const float*)d_in[3];
    const float* bc  = (const float*)d_in[4];
    const int*   src = (const int*)d_in[5];
    const int*   dst = (const int*)d_in[6];

    float* out = (float*)d_out;        // [0] = logits, [1..] = h (100000 x 64)
    float* h   = out + 1;

    // ws layout (4B elems): deg | partial | offs | cursor | blockSums |
    // colsum | csr.  Total ~8.0 MB.
    int*   deg       = (int*)d_ws;
    int*   partial   = deg + NN;
    int*   offs      = partial + NN;
    int*   cursor    = offs + NN;
    int*   blockSums = cursor + NN;
    float* colsum    = (float*)(blockSums + SCAN2_T);
    int*   csr       = (int*)(colsum + 64);

    hipMemsetAsync(deg, 0, NN * sizeof(int), stream);
    hipMemsetAsync(colsum, 0, 64 * sizeof(float), stream);

    degree_hist<<<2048, 256, 0, stream>>>(dst, deg);
    scan1<<<NB, 256, 0, stream>>>(deg, partial, blockSums);
    scan2<<<1, SCAN2_T, 0, stream>>>(blockSums);
    scan3<<<NB, 256, 0, stream>>>(partial, blockSums, offs, cursor);
    bucket_fill<<<2048, 256, 0, stream>>>(src, dst, cursor, csr);
    gather_transform_norm<<<4096, 256, 0, stream>>>(x, csr, offs, deg, W, b, h, colsum);
    finalize<<<1, 64, 0, stream>>>(colsum, wc, bc, out);
}